// Round 8
// baseline (709.579 us; speedup 1.0000x reference)
//
#include <hip/hip_runtime.h>
#include <hip/hip_fp16.h>
#include <math.h>
#include <stdint.h>

namespace {
constexpr float kDT  = 0.01f;   // DT / SUBSTEP, SUBSTEP == 1
constexpr int   kIter = 10;
constexpr float kH   = -2.0f;
constexpr float kEps = 1e-5f;
constexpr int   kB = 8;
constexpr int   kN = 50000;
constexpr int   kE = 200000;
constexpr int   kBN = kB * kN;
constexpr int   kE4 = kE * 4;             // per-half plane stride (edge, 4 batches)
constexpr int   kNB = (kN + 255) / 256;   // 196 blocks for per-vertex kernels
constexpr int   kBins = 64;               // degree bins (clamped)
constexpr int   kM = kBins * kNB;         // (bin, block) table size
constexpr int   kVCH = (kN + 63) / 64;    // 782 vertex chunks of 64
constexpr int   kSweepBlocks = ((kVCH + 3) / 4) * 8;   // 196*8
}

// ---------------- CSR build (once per launch) ----------------

__global__ void count_kernel(const int2* __restrict__ Cdist, int* __restrict__ deg) {
    int e = blockIdx.x * blockDim.x + threadIdx.x;
    if (e >= kE) return;
    int2 c = Cdist[e];
    atomicAdd(&deg[c.x], 1);
    atomicAdd(&deg[c.y], 1);
}

__global__ void partial_sum_kernel(const int* __restrict__ deg, int* __restrict__ blkSum) {
    __shared__ int s[256];
    int i = blockIdx.x * 256 + threadIdx.x;
    s[threadIdx.x] = (i < kN) ? deg[i] : 0;
    __syncthreads();
    for (int off = 128; off > 0; off >>= 1) {
        if (threadIdx.x < off) s[threadIdx.x] += s[threadIdx.x + off];
        __syncthreads();
    }
    if (threadIdx.x == 0) blkSum[blockIdx.x] = s[0];
}

__global__ void scan_sums_kernel(const int* __restrict__ blkSum, int* __restrict__ blkOff) {
    __shared__ int s[kNB];
    int tid = threadIdx.x;                 // 256 threads >= kNB
    if (tid < kNB) s[tid] = blkSum[tid];
    __syncthreads();
    if (tid == 0) {
        int acc = 0;
        for (int i = 0; i < kNB; ++i) { int v = s[i]; s[i] = acc; acc += v; }
    }
    __syncthreads();
    if (tid < kNB) blkOff[tid] = s[tid];
}

__global__ void scatter_scan_kernel(const int* __restrict__ deg,
                                    const int* __restrict__ blkOff,
                                    int* __restrict__ start) {
    __shared__ int s[256];
    int tid = threadIdx.x;
    int i = blockIdx.x * 256 + tid;
    int c = (i < kN) ? deg[i] : 0;
    s[tid] = c;
    __syncthreads();
    for (int off = 1; off < 256; off <<= 1) {      // inclusive Hillis-Steele
        int v = (tid >= off) ? s[tid - off] : 0;
        __syncthreads();
        s[tid] += v;
        __syncthreads();
    }
    int incl = s[tid];
    int excl = incl - c;
    if (i < kN) start[i] = blkOff[blockIdx.x] + excl;
    if (i == kN - 1) start[kN] = blkOff[blockIdx.x] + incl;   // == 2E
}

// inc id = 2*e + side. Fill order nondeterministic (atomics); it only permutes
// slot order within a vertex — per-edge math is order-independent here.
__global__ void fill_kernel(const int2* __restrict__ Cdist, int* __restrict__ cursor,
                            int* __restrict__ inc) {
    int e = blockIdx.x * blockDim.x + threadIdx.x;
    if (e >= kE) return;
    int2 c = Cdist[e];
    int p0 = atomicAdd(&cursor[c.x], 1);
    inc[p0] = 2 * e;
    int p1 = atomicAdd(&cursor[c.y], 1);
    inc[p1] = 2 * e + 1;
}

// ---------------- degree-sorted dispatch order (contention-free) ----------------

__device__ __forceinline__ int clamp_deg(int d) {
    return d > kBins - 1 ? kBins - 1 : d;
}

__global__ void blk_hist_kernel(const int* __restrict__ deg, int* __restrict__ blkHist) {
    __shared__ int lh[kBins];
    int tid = threadIdx.x;
    if (tid < kBins) lh[tid] = 0;
    __syncthreads();
    int v = blockIdx.x * 256 + tid;
    if (v < kN) atomicAdd(&lh[clamp_deg(deg[v])], 1);   // LDS atomic: cheap
    __syncthreads();
    if (tid < kBins) blkHist[(kBins - 1 - tid) * kNB + blockIdx.x] = lh[tid];
}

__global__ void sort_scan_kernel(const int* __restrict__ in, int* __restrict__ out) {
    __shared__ int part[1024];
    int tid = threadIdx.x;
    const int CH = (kM + 1023) / 1024;
    int lo = tid * CH;
    int hi = lo + CH; if (hi > kM) hi = kM;
    int s = 0;
    for (int m = lo; m < hi; ++m) s += in[m];
    part[tid] = s;
    __syncthreads();
    for (int off = 1; off < 1024; off <<= 1) {
        int v = (tid >= off) ? part[tid - off] : 0;
        __syncthreads();
        part[tid] += v;
        __syncthreads();
    }
    int base = tid ? part[tid - 1] : 0;
    for (int m = lo; m < hi; ++m) { out[m] = base; base += in[m]; }
}

// order[] only permutes which sorted position a vertex occupies; per-vertex
// math and output addresses are fixed by v, so results are unaffected.
__global__ void order_scatter_kernel(const int* __restrict__ deg,
                                     const int* __restrict__ scanned,
                                     int* __restrict__ order) {
    __shared__ int lh[kBins];
    int tid = threadIdx.x;
    if (tid < kBins) lh[tid] = 0;
    __syncthreads();
    int v = blockIdx.x * 256 + tid;
    if (v < kN) {
        int d = clamp_deg(deg[v]);
        int lr = atomicAdd(&lh[d], 1);                  // LDS atomic: cheap
        int pos = scanned[(kBins - 1 - d) * kNB + blockIdx.x] + lr;
        order[pos] = v;
    }
}

__global__ void rank_kernel(const int* __restrict__ order, int* __restrict__ rank) {
    int g = blockIdx.x * blockDim.x + threadIdx.x;
    if (g >= kN) return;
    rank[order[g]] = g;
}

__global__ void sd_kernel(const int* __restrict__ order, const int* __restrict__ start,
                          int2* __restrict__ SD) {
    int g = blockIdx.x * blockDim.x + threadIdx.x;
    if (g >= kN) return;
    int v = order[g];
    SD[g] = make_int2(start[v], start[v + 1]);
}

// ---------------- predict into sorted, batch-minor layout ----------------

// P[g][b] = {x,y,z predicted, w} at SORTED position g;  WC[g][b] = {w, comp}
__global__ void predict_kernel(const int* __restrict__ order,
                               const float* __restrict__ V,
                               const float* __restrict__ Vvel,
                               const float* __restrict__ Vw,
                               const float* __restrict__ Vcomp,
                               const float* __restrict__ Vmass,
                               const float* __restrict__ Vforce,
                               float4* __restrict__ P,
                               float2* __restrict__ WC) {
    int g = blockIdx.x * blockDim.x + threadIdx.x;
    if (g >= kN) return;
    int v = order[g];
#pragma unroll
    for (int b = 0; b < kB; ++b) {
        int idx = b * kN + v;
        int k = idx * 3;
        float m = Vmass[idx];
        float4 r;
        float vpx = Vvel[k + 0] + (kDT * Vforce[k + 0]) / m;   // (dt*F)/m, reference order
        float vpy = Vvel[k + 1] + (kDT * Vforce[k + 1]) / m;
        float vpz = Vvel[k + 2] + (kDT * Vforce[k + 2]) / m;
        float w = Vw[idx];
        r.x = V[k + 0] + kDT * vpx;
        r.y = V[k + 1] + kDT * vpy;
        r.z = V[k + 2] + kDT * vpz;
        r.w = w;
        P[g * 8 + b] = r;
        WC[g * 8 + b] = make_float2(w, Vcomp[idx]);
    }
}

// SS[k] = {rank[other], (e<<1)|side}
__global__ void ss_build_kernel(const int* __restrict__ inc,
                                const int2* __restrict__ Cdist,
                                const int* __restrict__ rank,
                                int2* __restrict__ SS) {
    int k = blockIdx.x * blockDim.x + threadIdx.x;
    if (k >= 2 * kE) return;
    int ic = inc[k];
    int e = ic >> 1;
    int side = ic & 1;
    int2 c = Cdist[e];
    int other = side ? c.x : c.y;
    SS[k] = make_int2(rank[other], (e << 1) | side);
}

// ASe[h][e][b4] = half2{A, 1/(S+A)}; EI[e] = init_d.  Iteration-invariant.
__global__ void ase_build_kernel(const int2* __restrict__ Cdist,
                                 const float* __restrict__ Cinit,
                                 const int* __restrict__ rank,
                                 const float2* __restrict__ WC,
                                 __half2* __restrict__ ASe,
                                 float* __restrict__ EI) {
    int e = blockIdx.x * blockDim.x + threadIdx.x;
    if (e >= kE) return;
    int2 c = Cdist[e];
    int gi = rank[c.x], gj = rank[c.y];
    EI[e] = Cinit[e];
#pragma unroll
    for (int b = 0; b < kB; ++b) {
        float2 wi = WC[gi * 8 + b];
        float2 wj = WC[gj * 8 + b];
        float A = (wi.y + wj.y) * 0.5f;
        float S = wi.x + wj.x;
        if (S == 0.0f) S = INFINITY;
        float rSA = 1.0f / (S + A);
        int h = b >> 2, b4 = b & 3;
        ASe[(size_t)h * kE4 + e * 4 + b4] = __floats2half2_rn(A, rSA);
    }
}

// ---------------- fused Jacobi sweep ----------------
// Block -> (half h, XCD c, chunk): bid%8 in {0..3} => h=0 (batches 0-3, XCDs
// 0-3), {4..7} => h=1. Per-XCD random working set (P-half 3.2MB, AS-half
// 3.2MB, L-half 3.2MB) is mostly L2-resident. Thread = (sorted vertex g,
// batch b4 of its half). Ld is bitwise identical from both endpoints; the
// side-0 slot writes the ping-pong L so every (e,b) is written exactly once.
template <bool LAST>
__global__ __launch_bounds__(256)
void sweep_kernel(const float4* __restrict__ Psrc,
                  float4* __restrict__ Pdst,
                  const float* __restrict__ Lsrc,
                  float* __restrict__ Ldst,
                  const int2* __restrict__ SS,
                  const __half2* __restrict__ ASe,
                  const float* __restrict__ EI,
                  const int2* __restrict__ SD,
                  const int* __restrict__ order,
                  const float* __restrict__ V,
                  float* __restrict__ outV,
                  float* __restrict__ outVel) {
    int bid = blockIdx.x;
    int c = bid & 3;
    int h = (bid >> 2) & 1;
    int schunk = (bid >> 3) * 4 + c;
    if (schunk >= kVCH) return;
    int gi = threadIdx.x >> 2;
    int b4 = threadIdx.x & 3;
    int g = schunk * 64 + gi;
    if (g >= kN) return;
    int hb = h * 4 + b4;                    // batch index

    float4 own = Psrc[(size_t)g * 8 + hb];  // coalesced (sorted layout)
    int2 sd = SD[g];
    const __half2* ASh = ASe + (size_t)h * kE4;
    const float*   Lsh = Lsrc + (size_t)h * kE4;
    float*         Ldh = Ldst + (size_t)h * kE4;

    float ax = 0.f, ay = 0.f, az = 0.f;
    for (int k = sd.x; k < sd.y; ++k) {
        int2 ss = SS[k];                    // broadcast across the 4 lanes
        int e = ss.y >> 1;
        float4 oth = Psrc[(size_t)ss.x * 8 + hb];   // 64B line, L2-resident half
        float Lold = Lsh[e * 4 + b4];
        __half2 a2 = ASh[e * 4 + b4];
        float dx = own.x - oth.x;
        float dy = own.y - oth.y;
        float dz = own.z - oth.z;
        float D = sqrtf(dx * dx + dy * dy + dz * dz);
        float C = D - EI[e];
        float A = __low2float(a2);
        float rSA = __high2float(a2);
        float Ld = (-C - A * Lold) * rSA;
        if (!(ss.y & 1)) Ldh[e * 4 + b4] = Lold + Ld;   // side-0 owns the write
        float rD = 1.0f / D;
        ax += Ld * (dx * rD);
        ay += Ld * (dy * rD);
        az += Ld * (dz * rD);
    }
    float px = own.x + own.w * ax;
    float py = own.y + own.w * ay;
    float pz = own.z + own.w * az;
    if (!LAST) {
        Pdst[(size_t)g * 8 + hb] = make_float4(px, py, pz, own.w);
    } else {
        int v = order[g];
        int k3 = (hb * kN + v) * 3;
        float vx = V[k3], vy = V[k3 + 1], vz0 = V[k3 + 2];

        bool col = (pz < kH) && (vz0 > kH);
        float h_prev = vz0 - kH;
        float h_after = kH - pz;
        float denom = col ? (h_prev + h_after) : 1.0f;
        float tt = h_prev / denom;

        float x  = col ? (vx + tt * (px - vx)) : px;
        float y  = col ? (vy + tt * (py - vy)) : py;
        float z1 = col ? (kH + kEps) : pz;

        bool vio = (z1 < kH) && (vz0 < kH);
        float z2 = vio ? (kH + kEps) : z1;

        float velx = (x  - vx ) / kDT;
        float vely = (y  - vy ) / kDT;
        float velz = (z2 - vz0) / kDT;
        velz = col ? -velz : velz;
        velz = vio ? 0.0f : velz;

        outV[k3] = x;  outV[k3 + 1] = y;  outV[k3 + 2] = z2;
        outVel[k3] = velx; outVel[k3 + 1] = vely; outVel[k3 + 2] = velz;
    }
}

// ---------------- launch ----------------

extern "C" void kernel_launch(void* const* d_in, const int* in_sizes, int n_in,
                              void* d_out, int out_size, void* d_ws, size_t ws_size,
                              hipStream_t stream) {
    const float* V      = (const float*)d_in[0];
    const float* Vvel   = (const float*)d_in[1];
    const float* Vw     = (const float*)d_in[2];
    const float* Vcomp  = (const float*)d_in[3];
    const float* Vmass  = (const float*)d_in[4];
    const float* Vforce = (const float*)d_in[5];
    const float* Cinit  = (const float*)d_in[6];
    const int2*  Cdist  = (const int2*)d_in[7];

    char* p = (char*)d_ws;
    auto alloc = [&](size_t bytes) -> void* {
        p = (char*)(((uintptr_t)p + 255) & ~(uintptr_t)255);
        void* r = (void*)p;
        p += bytes;
        return r;
    };

    float4*  PA     = (float4*)alloc((size_t)kN * 8 * sizeof(float4));      // 6.4 MB
    float4*  PB     = (float4*)alloc((size_t)kN * 8 * sizeof(float4));      // 6.4 MB
    float*   LA     = (float*)alloc((size_t)2 * kE4 * sizeof(float));       // 6.4 MB
    float*   LB     = (float*)alloc((size_t)2 * kE4 * sizeof(float));       // 6.4 MB
    __half2* ASe    = (__half2*)alloc((size_t)2 * kE4 * sizeof(__half2));   // 6.4 MB
    float*   EI     = (float*)alloc((size_t)kE * sizeof(float));            // 0.8 MB
    int2*    SS     = (int2*)alloc((size_t)2 * kE * sizeof(int2));          // 3.2 MB
    float2*  WC     = (float2*)alloc((size_t)kN * 8 * sizeof(float2));      // 3.2 MB
    int2*    SD     = (int2*)alloc((size_t)kN * sizeof(int2));
    int*     start  = (int*)alloc((size_t)(kN + 1) * sizeof(int));
    int*     deg    = (int*)alloc((size_t)kN * sizeof(int));
    int*     cursor = (int*)alloc((size_t)kN * sizeof(int));
    int*     inc    = (int*)alloc((size_t)2 * kE * sizeof(int));
    int*     blkSum = (int*)alloc((size_t)kNB * sizeof(int));
    int*     blkOff = (int*)alloc((size_t)kNB * sizeof(int));
    int*     blkHist= (int*)alloc((size_t)kM * sizeof(int));
    int*     scanned= (int*)alloc((size_t)kM * sizeof(int));
    int*     order  = (int*)alloc((size_t)kN * sizeof(int));
    int*     rank   = (int*)alloc((size_t)kN * sizeof(int));

    const int TB = 256;
    dim3 blk(TB);
    dim3 gE((kE + TB - 1) / TB);
    dim3 g2E((2 * kE + TB - 1) / TB);
    dim3 gN(kNB);

    // CSR build
    hipMemsetAsync(deg, 0, kN * sizeof(int), stream);
    count_kernel<<<gE, blk, 0, stream>>>(Cdist, deg);
    partial_sum_kernel<<<dim3(kNB), blk, 0, stream>>>(deg, blkSum);
    scan_sums_kernel<<<dim3(1), blk, 0, stream>>>(blkSum, blkOff);
    scatter_scan_kernel<<<dim3(kNB), blk, 0, stream>>>(deg, blkOff, start);
    hipMemcpyAsync(cursor, start, kN * sizeof(int), hipMemcpyDeviceToDevice, stream);
    fill_kernel<<<gE, blk, 0, stream>>>(Cdist, cursor, inc);

    // degree-sorted dispatch order + rank + per-g slot ranges
    blk_hist_kernel<<<gN, blk, 0, stream>>>(deg, blkHist);
    sort_scan_kernel<<<dim3(1), dim3(1024), 0, stream>>>(blkHist, scanned);
    order_scatter_kernel<<<gN, blk, 0, stream>>>(deg, scanned, order);
    rank_kernel<<<gN, blk, 0, stream>>>(order, rank);
    sd_kernel<<<gN, blk, 0, stream>>>(order, start, SD);

    // predict into sorted layout, then iteration-invariant edge data
    predict_kernel<<<gN, blk, 0, stream>>>(order, V, Vvel, Vw, Vcomp, Vmass, Vforce, PA, WC);
    ss_build_kernel<<<g2E, blk, 0, stream>>>(inc, Cdist, rank, SS);
    ase_build_kernel<<<gE, blk, 0, stream>>>(Cdist, Cinit, rank, WC, ASe, EI);
    hipMemsetAsync(LA, 0, (size_t)2 * kE4 * sizeof(float), stream);

    float* outV   = (float*)d_out;
    float* outVel = outV + (size_t)kBN * 3;

    dim3 gS(kSweepBlocks);
    for (int it = 0; it < kIter; ++it) {
        float4* src = (it & 1) ? PB : PA;
        float4* dst = (it & 1) ? PA : PB;
        float*  ls  = (it & 1) ? LB : LA;
        float*  ld  = (it & 1) ? LA : LB;
        if (it < kIter - 1) {
            sweep_kernel<false><<<gS, blk, 0, stream>>>(src, dst, ls, ld, SS, ASe, EI,
                                                        SD, order, V, outV, outVel);
        } else {
            sweep_kernel<true><<<gS, blk, 0, stream>>>(src, dst, ls, ld, SS, ASe, EI,
                                                       SD, order, V, outV, outVel);
        }
    }
}